// Round 8
// baseline (217.541 us; speedup 1.0000x reference)
//
#include <hip/hip_runtime.h>

#define TB 256
#define NGRP 8            // XCDs on MI355X; blockIdx%8 round-robins across XCDs
#define NB_P 256          // partition blocks
#define TBP 256           // partition block threads
#define NBKT 256          // dst-range buckets (32 per XCD)
#define SORT_T 1024

typedef int      i4v __attribute__((ext_vector_type(4)));
typedef float    f4v __attribute__((ext_vector_type(4)));
typedef _Float16 h4v __attribute__((ext_vector_type(4)));

template <int W> struct HVec { typedef _Float16 type __attribute__((ext_vector_type(W))); };

static __device__ __forceinline__ float leaky(float x) {
  return x > 0.f ? x : 0.2f * x;
}

// ================= CSR build: 256-bucket partition + per-bucket LDS sort =================

// A1: per-block bucket counts (LDS), cnt laid out [bucket][block] for coalesced scan.
__global__ void k_bcount(const int* __restrict__ dstA, int* __restrict__ cnt,
                         int E4, int E, unsigned M, int CH4) {
  __shared__ int lc[NBKT];
  for (int i = threadIdx.x; i < NBKT; i += TBP) lc[i] = 0;
  __syncthreads();
  const int bstart = blockIdx.x * CH4;
  const int bend = min(E4, bstart + CH4);
  const i4v* d4 = reinterpret_cast<const i4v*>(dstA);
  for (int i = bstart + threadIdx.x; i < bend; i += TBP) {
    i4v d = __builtin_nontemporal_load(&d4[i]);
#pragma unroll
    for (int k = 0; k < 4; ++k) atomicAdd(&lc[__umulhi((unsigned)d[k], M)], 1);
  }
  if (blockIdx.x == NB_P - 1) {
    for (int t = E4 * 4 + threadIdx.x; t < E; t += TBP)
      atomicAdd(&lc[__umulhi((unsigned)dstA[t], M)], 1);
  }
  __syncthreads();
  for (int b = threadIdx.x; b < NBKT; b += TBP) cnt[b * NB_P + blockIdx.x] = lc[b];
}

// A2a: per-bucket exclusive scan over blocks (grid = NBKT, block = NB_P threads).
__global__ void k_bscan1(const int* __restrict__ cnt, int* __restrict__ off,
                         int* __restrict__ colTotal) {
  __shared__ int sh[NB_P];
  const int t = threadIdx.x;
  const int b = blockIdx.x;
  int v = cnt[b * NB_P + t];
  sh[t] = v;
  __syncthreads();
  for (int o = 1; o < NB_P; o <<= 1) {
    int u = (t >= o) ? sh[t - o] : 0;
    __syncthreads();
    sh[t] += u;
    __syncthreads();
  }
  off[b * NB_P + t] = sh[t] - v;
  if (t == NB_P - 1) colTotal[b] = sh[t];
}

// A2b: exclusive scan of bucket totals -> bucketBase[NBKT+1].
__global__ void k_bscan2(const int* __restrict__ colTotal, int* __restrict__ bucketBase) {
  __shared__ int sh[NBKT];
  const int t = threadIdx.x;
  int v = colTotal[t];
  sh[t] = v;
  __syncthreads();
  for (int o = 1; o < NBKT; o <<= 1) {
    int u = (t >= o) ? sh[t - o] : 0;
    __syncthreads();
    sh[t] += u;
    __syncthreads();
  }
  bucketBase[t] = sh[t] - v;
  if (t == NBKT - 1) bucketBase[NBKT] = sh[t];
}

// A3: scatter packed (dloc<<17 | src) into bucket segments via LDS cursors.
__global__ void k_bscatter(const int* __restrict__ srcA, const int* __restrict__ dstA,
                           const int* __restrict__ off, const int* __restrict__ bucketBase,
                           int* __restrict__ epk, int E4, int E, unsigned M, int R, int CH4) {
  __shared__ int lcur[NBKT];
  for (int i = threadIdx.x; i < NBKT; i += TBP)
    lcur[i] = bucketBase[i] + off[i * NB_P + blockIdx.x];
  __syncthreads();
  const int bstart = blockIdx.x * CH4;
  const int bend = min(E4, bstart + CH4);
  const i4v* d4 = reinterpret_cast<const i4v*>(dstA);
  const i4v* s4 = reinterpret_cast<const i4v*>(srcA);
  for (int i = bstart + threadIdx.x; i < bend; i += TBP) {
    i4v d = __builtin_nontemporal_load(&d4[i]);
    i4v sv = __builtin_nontemporal_load(&s4[i]);
#pragma unroll
    for (int k = 0; k < 4; ++k) {
      int dd = d[k];
      int b = __umulhi((unsigned)dd, M);
      int pos = atomicAdd(&lcur[b], 1);
      epk[pos] = ((dd - b * R) << 17) | sv[k];
    }
  }
  if (blockIdx.x == NB_P - 1) {
    for (int t = E4 * 4 + threadIdx.x; t < E; t += TBP) {
      int dd = dstA[t];
      int b = __umulhi((unsigned)dd, M);
      int pos = atomicAdd(&lcur[b], 1);
      epk[pos] = ((dd - b * R) << 17) | srcA[t];
    }
  }
}

// B: per-bucket counting sort in LDS -> rowStart slice + colIdx segment.
// Bucket b mapped so XCD g = b/32 processes its own node range.
__global__ void k_bsort(const int* __restrict__ epk, const int* __restrict__ bucketBase,
                        int* __restrict__ rowStart, int* __restrict__ colIdx,
                        int N, int R, int E) {
  __shared__ int sc[512];
  const int b = (blockIdx.x & (NGRP - 1)) * (NBKT / NGRP) + (blockIdx.x >> 3);
  const int lo = bucketBase[b], hi = bucketBase[b + 1];
  const int nodeLo = b * R;
  const int nN = min(R, N - nodeLo);
  const int t = threadIdx.x;
  if (t < 512) sc[t] = 0;
  __syncthreads();
  for (int i = lo + t; i < hi; i += SORT_T) {
    int pk = __builtin_nontemporal_load(&epk[i]);
    atomicAdd(&sc[pk >> 17], 1);
  }
  __syncthreads();
  int own = (t < 512) ? sc[t] : 0;
  for (int o = 1; o < 512; o <<= 1) {
    int u = (t < 512 && t >= o) ? sc[t - o] : 0;
    __syncthreads();
    if (t < 512) sc[t] += u;
    __syncthreads();
  }
  if (t < nN) rowStart[nodeLo + t] = lo + sc[t] - own;
  if (b == NBKT - 1 && t == 0) rowStart[N] = E;
  if (t < 512) sc[t] -= own;  // exclusive offsets become LDS cursors
  __syncthreads();
  for (int i = lo + t; i < hi; i += SORT_T) {
    int pk = __builtin_nontemporal_load(&epk[i]);
    int pos = lo + atomicAdd(&sc[pk >> 17], 1);
    colIdx[pos] = pk & 0x1FFFF;
  }
}

// ================= node transform: SPLIT threads/node, shuffle-combined =================

template <int IN, int H, int C, int SPLIT, bool NT>
__global__ void k_node(const float* __restrict__ xin, const float* __restrict__ W,
                       const float* __restrict__ a_src, const float* __restrict__ a_dst,
                       _Float16* __restrict__ hout, float* __restrict__ as_,
                       float* __restrict__ ad_, int N) {
  constexpr int OUT = H * C;
  constexpr int PIN4 = IN / SPLIT / 4;   // float4 loads per thread
  constexpr int NPB = TB / SPLIT;
  __shared__ float Ws[IN * OUT];
  __shared__ float As[OUT], Ad[OUT];
  for (int i = threadIdx.x; i < IN * OUT; i += blockDim.x) Ws[i] = W[i];
  if (threadIdx.x < OUT) {
    As[threadIdx.x] = a_src[threadIdx.x];
    Ad[threadIdx.x] = a_dst[threadIdx.x];
  }
  __syncthreads();
  const int j = threadIdx.x & (SPLIT - 1);
  const int n = blockIdx.x * NPB + threadIdx.x / SPLIT;
  if (n >= N) return;
  float acc[OUT];
#pragma unroll
  for (int q = 0; q < OUT; ++q) acc[q] = 0.f;
  const f4v* x4 = reinterpret_cast<const f4v*>(xin + (size_t)n * IN + j * (IN / SPLIT));
#pragma unroll
  for (int k4 = 0; k4 < PIN4; ++k4) {
    f4v xv = NT ? __builtin_nontemporal_load(&x4[k4]) : x4[k4];
    const int kb = j * (IN / SPLIT) + 4 * k4;
#pragma unroll
    for (int q = 0; q < OUT; ++q) {
      acc[q] += xv[0] * Ws[(kb + 0) * OUT + q];
      acc[q] += xv[1] * Ws[(kb + 1) * OUT + q];
      acc[q] += xv[2] * Ws[(kb + 2) * OUT + q];
      acc[q] += xv[3] * Ws[(kb + 3) * OUT + q];
    }
  }
#pragma unroll
  for (int o = 1; o < SPLIT; o <<= 1) {
#pragma unroll
    for (int q = 0; q < OUT; ++q) acc[q] += __shfl_xor(acc[q], o);
  }
  constexpr int WCH = OUT / 4;  // h4v chunks
  if (j < WCH) {
    h4v v;
    v[0] = (_Float16)acc[4 * j + 0];
    v[1] = (_Float16)acc[4 * j + 1];
    v[2] = (_Float16)acc[4 * j + 2];
    v[3] = (_Float16)acc[4 * j + 3];
    reinterpret_cast<h4v*>(hout + (size_t)n * OUT)[j] = v;
  }
  if (j < H) {
    float ss = 0.f, dd = 0.f;
#pragma unroll
    for (int c = 0; c < C; ++c) {
      ss += acc[j * C + c] * As[j * C + c];
      dd += acc[j * C + c] * Ad[j * C + c];
    }
    as_[n * H + j] = ss;
    ad_[n * H + j] = dd;
  }
}

// ================= edge aggregation =================
// L feature-lanes (HVW halfs each, within one head) x S edge-split sub-lanes.
// colIdx read as 16B-aligned int4 chunks of 4 edges; out-of-range slots masked
// (p=0, src=n). Direct exp (logits bounded); shuffle combine over S.

template <int H, int C, int L, int HVW, int S, bool RELU>
__global__ void k_edge(const int* __restrict__ rowStart, const int* __restrict__ colIdx,
                       const _Float16* __restrict__ hfeat, const float* __restrict__ as_,
                       const float* __restrict__ ad_, const float* __restrict__ bias,
                       float* __restrict__ out, int N, int R8) {
  constexpr int OUT = H * C;
  static_assert(OUT == L * HVW && C % HVW == 0, "lane layout");
  constexpr int LS = L * S;
  constexpr int NPB = TB / LS;
  typedef typename HVec<HVW>::type hvec;
  const int g = blockIdx.x & (NGRP - 1);
  const int lb = blockIdx.x / NGRP;
  const int lane = threadIdx.x % LS;
  const int sub = lane / L;
  const int j = lane % L;
  const int n = g * R8 + lb * NPB + threadIdx.x / LS;
  const int nEnd = min((g + 1) * R8, N);
  if (n >= nEnd) return;
  const int hh = (j * HVW) / C;
  const float adv = ad_[n * H + hh];
  const int start = rowStart[n];
  const int end = rowStart[n + 1];
  float s = 0.f, acc[HVW];
#pragma unroll
  for (int q = 0; q < HVW; ++q) acc[q] = 0.f;
  if (sub == 0) {  // self-loop
    float p = __expf(leaky(as_[n * H + hh] + adv));
    hvec a0 = reinterpret_cast<const hvec*>(hfeat + (size_t)n * OUT)[j];
    s = p;
#pragma unroll
    for (int q = 0; q < HVW; ++q) acc[q] = p * (float)a0[q];
  }
  const int base = start & ~3;
  const int nch = (end - base + 3) >> 2;
  for (int t = sub; t < nch; t += S) {
    const int i0 = base + 4 * t;
    i4v cv = *reinterpret_cast<const i4v*>(colIdx + i0);
#pragma unroll
    for (int k = 0; k < 4; ++k) {
      const bool ok = (i0 + k >= start) && (i0 + k < end);
      const int src = ok ? cv[k] : n;
      hvec hv = reinterpret_cast<const hvec*>(hfeat + (size_t)src * OUT)[j];
      float e = as_[src * H + hh];
      float p = ok ? __expf(leaky(e + adv)) : 0.f;
      s += p;
#pragma unroll
      for (int q = 0; q < HVW; ++q) acc[q] += p * (float)hv[q];
    }
  }
#pragma unroll
  for (int off = L; off < LS; off <<= 1) {
    s += __shfl_xor(s, off);
#pragma unroll
    for (int q = 0; q < HVW; ++q) acc[q] += __shfl_xor(acc[q], off);
  }
  if (sub == 0) {
    float inv = 1.f / (s + 1e-16f);
#pragma unroll
    for (int q4 = 0; q4 < HVW / 4; ++q4) {
      float4 bb = reinterpret_cast<const float4*>(bias)[j * (HVW / 4) + q4];
      float4 o;
      o.x = acc[4 * q4 + 0] * inv + bb.x;
      o.y = acc[4 * q4 + 1] * inv + bb.y;
      o.z = acc[4 * q4 + 2] * inv + bb.z;
      o.w = acc[4 * q4 + 3] * inv + bb.w;
      if (RELU) {
        o.x = fmaxf(o.x, 0.f);
        o.y = fmaxf(o.y, 0.f);
        o.z = fmaxf(o.z, 0.f);
        o.w = fmaxf(o.w, 0.f);
      }
      reinterpret_cast<float4*>(out + (size_t)n * OUT)[j * (HVW / 4) + q4] = o;
    }
  }
}

// layer-3 (H=1,C=4) edge aggregation + fused classifier; S=8 edge-split, chunked
__global__ void k_edge3(const int* __restrict__ rowStart, const int* __restrict__ colIdx,
                        const _Float16* __restrict__ hfeat, const float* __restrict__ as_,
                        const float* __restrict__ ad_, const float* __restrict__ b3,
                        const float* __restrict__ Wc, const float* __restrict__ bc,
                        float* __restrict__ out, int N, int R8) {
  constexpr int S = 8;
  constexpr int NPB = TB / S;
  const int g = blockIdx.x & (NGRP - 1);
  const int lb = blockIdx.x / NGRP;
  const int sub = threadIdx.x % S;
  const int n = g * R8 + lb * NPB + threadIdx.x / S;
  const int nEnd = min((g + 1) * R8, N);
  if (n >= nEnd) return;
  const float adv = ad_[n];
  const int start = rowStart[n];
  const int end = rowStart[n + 1];
  float s = 0.f, acc0 = 0.f, acc1 = 0.f, acc2 = 0.f, acc3 = 0.f;
  if (sub == 0) {
    float p = __expf(leaky(as_[n] + adv));
    h4v a0 = reinterpret_cast<const h4v*>(hfeat)[n];
    s = p;
    acc0 = p * (float)a0[0];
    acc1 = p * (float)a0[1];
    acc2 = p * (float)a0[2];
    acc3 = p * (float)a0[3];
  }
  const int base = start & ~3;
  const int nch = (end - base + 3) >> 2;
  for (int t = sub; t < nch; t += S) {
    const int i0 = base + 4 * t;
    i4v cv = *reinterpret_cast<const i4v*>(colIdx + i0);
#pragma unroll
    for (int k = 0; k < 4; ++k) {
      const bool ok = (i0 + k >= start) && (i0 + k < end);
      const int src = ok ? cv[k] : n;
      h4v hv = reinterpret_cast<const h4v*>(hfeat)[src];
      float e = as_[src];
      float p = ok ? __expf(leaky(e + adv)) : 0.f;
      s += p;
      acc0 += p * (float)hv[0];
      acc1 += p * (float)hv[1];
      acc2 += p * (float)hv[2];
      acc3 += p * (float)hv[3];
    }
  }
#pragma unroll
  for (int off = 1; off < S; off <<= 1) {
    s += __shfl_xor(s, off);
    acc0 += __shfl_xor(acc0, off);
    acc1 += __shfl_xor(acc1, off);
    acc2 += __shfl_xor(acc2, off);
    acc3 += __shfl_xor(acc3, off);
  }
  if (sub == 0) {
    float inv = 1.f / (s + 1e-16f);
    float o0 = acc0 * inv + b3[0];
    float o1 = acc1 * inv + b3[1];
    float o2 = acc2 * inv + b3[2];
    float o3 = acc3 * inv + b3[3];
    float2 r;
    r.x = o0 * Wc[0] + o1 * Wc[2] + o2 * Wc[4] + o3 * Wc[6] + bc[0];
    r.y = o0 * Wc[1] + o1 * Wc[3] + o2 * Wc[5] + o3 * Wc[7] + bc[1];
    reinterpret_cast<float2*>(out)[n] = r;
  }
}

// ================= launch =================

extern "C" void kernel_launch(void* const* d_in, const int* in_sizes, int n_in,
                              void* d_out, int out_size, void* d_ws, size_t ws_size,
                              hipStream_t stream) {
  const float* x    = (const float*)d_in[0];
  const int*   ei   = (const int*)d_in[1];
  const float* W1   = (const float*)d_in[2];
  const float* as1w = (const float*)d_in[3];
  const float* ad1w = (const float*)d_in[4];
  const float* b1   = (const float*)d_in[5];
  const float* W2   = (const float*)d_in[6];
  const float* as2w = (const float*)d_in[7];
  const float* ad2w = (const float*)d_in[8];
  const float* b2   = (const float*)d_in[9];
  const float* W3   = (const float*)d_in[10];
  const float* as3w = (const float*)d_in[11];
  const float* ad3w = (const float*)d_in[12];
  const float* b3   = (const float*)d_in[13];
  const float* Wc   = (const float*)d_in[14];
  const float* bc   = (const float*)d_in[15];
  float* out = (float*)d_out;

  const int N = in_sizes[0] / 128;
  const int E = in_sizes[1] / 2;
  const int* srcA = ei;
  const int* dstA = ei + E;

  char* p = (char*)d_ws;
  auto alloc = [&](size_t bytes) -> void* {
    void* r = (void*)p;
    p += (bytes + 255) & ~(size_t)255;
    return r;
  };
  int* cnt        = (int*)alloc((size_t)NBKT * NB_P * 4);
  int* off        = (int*)alloc((size_t)NBKT * NB_P * 4);
  int* colTotal   = (int*)alloc(NBKT * 4);
  int* bucketBase = (int*)alloc((NBKT + 1) * 4);
  int* rowStart   = (int*)alloc((size_t)(N + 1) * 4);
  int* epk        = (int*)alloc((size_t)E * 4);
  int* colIdx     = (int*)alloc((size_t)E * 4 + 256);
  _Float16* h1 = (_Float16*)alloc((size_t)N * 16 * 2);
  float* as1 = (float*)alloc((size_t)N * 2 * 4);
  float* ad1 = (float*)alloc((size_t)N * 2 * 4);
  float* o1  = (float*)alloc((size_t)N * 16 * 4);
  _Float16* h2 = (_Float16*)alloc((size_t)N * 8 * 2);
  float* as2 = (float*)alloc((size_t)N * 2 * 4);
  float* ad2 = (float*)alloc((size_t)N * 2 * 4);
  float* o2  = (float*)alloc((size_t)N * 8 * 4);
  _Float16* h3 = (_Float16*)alloc((size_t)N * 4 * 2);
  float* as3 = (float*)alloc((size_t)N * 4);
  float* ad3 = (float*)alloc((size_t)N * 4);

  const int R   = (N + NBKT - 1) / NBKT;                       // nodes per bucket (391)
  const unsigned M = (unsigned)(((1ULL << 32) + R - 1) / R);   // exact /R via __umulhi
  const int R8  = R * (NBKT / NGRP);                           // nodes per XCD (12512)
  const int E4  = E >> 2;
  const int CH4 = (E4 + NB_P - 1) / NB_P;

  // CSR build (no global atomics)
  k_bcount<<<NB_P, TBP, 0, stream>>>(dstA, cnt, E4, E, M, CH4);
  k_bscan1<<<NBKT, NB_P, 0, stream>>>(cnt, off, colTotal);
  k_bscan2<<<1, NBKT, 0, stream>>>(colTotal, bucketBase);
  k_bscatter<<<NB_P, TBP, 0, stream>>>(srcA, dstA, off, bucketBase, epk, E4, E, M, R, CH4);
  k_bsort<<<NBKT, SORT_T, 0, stream>>>(epk, bucketBase, rowStart, colIdx, N, R, E);

  // node-kernel grids: ceil(N / (TB/SPLIT))
  const int nb1 = (N + (TB / 4) - 1) / (TB / 4);
  const int nb2 = (N + (TB / 2) - 1) / (TB / 2);
  // edge-kernel grids: all use LS=8 -> 32 nodes/block
  const int ge = NGRP * ((R8 + (TB / 8) - 1) / (TB / 8));

  // layer 1: in=128, H=2, C=8  (L=2 x 16B gathers, S=4)
  k_node<128, 2, 8, 4, true><<<nb1, TB, 0, stream>>>(x, W1, as1w, ad1w, h1, as1, ad1, N);
  k_edge<2, 8, 2, 8, 4, true><<<ge, TB, 0, stream>>>(rowStart, colIdx, h1, as1, ad1, b1, o1, N, R8);

  // layer 2: in=16, H=2, C=4  (L=2 x 8B gathers, S=4)
  k_node<16, 2, 4, 2, false><<<nb2, TB, 0, stream>>>(o1, W2, as2w, ad2w, h2, as2, ad2, N);
  k_edge<2, 4, 2, 4, 4, true><<<ge, TB, 0, stream>>>(rowStart, colIdx, h2, as2, ad2, b2, o2, N, R8);

  // layer 3: in=8, H=1, C=4 + fused classifier (S=8)
  k_node<8, 1, 4, 2, false><<<nb2, TB, 0, stream>>>(o2, W3, as3w, ad3w, h3, as3, ad3, N);
  k_edge3<<<ge, TB, 0, stream>>>(rowStart, colIdx, h3, as3, ad3, b3, Wc, bc, out, N, R8);
}

// Round 9
// 201.919 us; speedup vs baseline: 1.0774x; 1.0774x over previous
//
#include <hip/hip_runtime.h>

#define TB 256
#define NGRP 8            // XCDs on MI355X
#define NB_P 256          // partition blocks
#define TBP 256           // partition block threads
#define NBKT 256          // dst-range buckets (32 per XCD)
#define SORT_T 1024
#define STG_CAP 14336     // LDS staging entries in k_bsort (56 KB)

typedef int      i4v __attribute__((ext_vector_type(4)));
typedef float    f4v __attribute__((ext_vector_type(4)));
typedef _Float16 h4v __attribute__((ext_vector_type(4)));
typedef _Float16 h8v __attribute__((ext_vector_type(8)));

static __device__ __forceinline__ float leaky(float x) {
  return x > 0.f ? x : 0.2f * x;
}

// ================= CSR build: 256-bucket partition + per-bucket LDS sort =================

__global__ void k_bcount(const int* __restrict__ dstA, int* __restrict__ cnt,
                         int E4, int E, unsigned M, int CH4) {
  __shared__ int lc[NBKT];
  for (int i = threadIdx.x; i < NBKT; i += TBP) lc[i] = 0;
  __syncthreads();
  const int bstart = blockIdx.x * CH4;
  const int bend = min(E4, bstart + CH4);
  const i4v* d4 = reinterpret_cast<const i4v*>(dstA);
  for (int i = bstart + threadIdx.x; i < bend; i += TBP) {
    i4v d = __builtin_nontemporal_load(&d4[i]);
#pragma unroll
    for (int k = 0; k < 4; ++k) atomicAdd(&lc[__umulhi((unsigned)d[k], M)], 1);
  }
  if (blockIdx.x == NB_P - 1) {
    for (int t = E4 * 4 + threadIdx.x; t < E; t += TBP)
      atomicAdd(&lc[__umulhi((unsigned)dstA[t], M)], 1);
  }
  __syncthreads();
  for (int b = threadIdx.x; b < NBKT; b += TBP) cnt[b * NB_P + blockIdx.x] = lc[b];
}

__global__ void k_bscan1(const int* __restrict__ cnt, int* __restrict__ off,
                         int* __restrict__ colTotal) {
  __shared__ int sh[NB_P];
  const int t = threadIdx.x;
  const int b = blockIdx.x;
  int v = cnt[b * NB_P + t];
  sh[t] = v;
  __syncthreads();
  for (int o = 1; o < NB_P; o <<= 1) {
    int u = (t >= o) ? sh[t - o] : 0;
    __syncthreads();
    sh[t] += u;
    __syncthreads();
  }
  off[b * NB_P + t] = sh[t] - v;
  if (t == NB_P - 1) colTotal[b] = sh[t];
}

__global__ void k_bscan2(const int* __restrict__ colTotal, int* __restrict__ bucketBase) {
  __shared__ int sh[NBKT];
  const int t = threadIdx.x;
  int v = colTotal[t];
  sh[t] = v;
  __syncthreads();
  for (int o = 1; o < NBKT; o <<= 1) {
    int u = (t >= o) ? sh[t - o] : 0;
    __syncthreads();
    sh[t] += u;
    __syncthreads();
  }
  bucketBase[t] = sh[t] - v;
  if (t == NBKT - 1) bucketBase[NBKT] = sh[t];
}

__global__ void k_bscatter(const int* __restrict__ srcA, const int* __restrict__ dstA,
                           const int* __restrict__ off, const int* __restrict__ bucketBase,
                           int* __restrict__ epk, int E4, int E, unsigned M, int R, int CH4) {
  __shared__ int lcur[NBKT];
  for (int i = threadIdx.x; i < NBKT; i += TBP)
    lcur[i] = bucketBase[i] + off[i * NB_P + blockIdx.x];
  __syncthreads();
  const int bstart = blockIdx.x * CH4;
  const int bend = min(E4, bstart + CH4);
  const i4v* d4 = reinterpret_cast<const i4v*>(dstA);
  const i4v* s4 = reinterpret_cast<const i4v*>(srcA);
  for (int i = bstart + threadIdx.x; i < bend; i += TBP) {
    i4v d = __builtin_nontemporal_load(&d4[i]);
    i4v sv = __builtin_nontemporal_load(&s4[i]);
#pragma unroll
    for (int k = 0; k < 4; ++k) {
      int dd = d[k];
      int b = __umulhi((unsigned)dd, M);
      int pos = atomicAdd(&lcur[b], 1);
      epk[pos] = ((dd - b * R) << 17) | sv[k];
    }
  }
  if (blockIdx.x == NB_P - 1) {
    for (int t = E4 * 4 + threadIdx.x; t < E; t += TBP) {
      int dd = dstA[t];
      int b = __umulhi((unsigned)dd, M);
      int pos = atomicAdd(&lcur[b], 1);
      epk[pos] = ((dd - b * R) << 17) | srcA[t];
    }
  }
}

// B: per-bucket counting sort; scatter into LDS staging, coalesced global write.
__global__ void k_bsort(const int* __restrict__ epk, const int* __restrict__ bucketBase,
                        int* __restrict__ rowStart, int* __restrict__ colIdx,
                        int N, int R, int E) {
  __shared__ int sc[512];
  __shared__ int stg[STG_CAP];
  const int b = (blockIdx.x & (NGRP - 1)) * (NBKT / NGRP) + (blockIdx.x >> 3);
  const int lo = bucketBase[b], hi = bucketBase[b + 1];
  const int cnt = hi - lo;
  const int nodeLo = b * R;
  const int nN = min(R, N - nodeLo);
  const int t = threadIdx.x;
  if (t < 512) sc[t] = 0;
  __syncthreads();
  for (int i = lo + t; i < hi; i += SORT_T) {
    int pk = __builtin_nontemporal_load(&epk[i]);
    atomicAdd(&sc[pk >> 17], 1);
  }
  __syncthreads();
  int own = (t < 512) ? sc[t] : 0;
  for (int o = 1; o < 512; o <<= 1) {
    int u = (t < 512 && t >= o) ? sc[t - o] : 0;
    __syncthreads();
    if (t < 512) sc[t] += u;
    __syncthreads();
  }
  if (t < nN) rowStart[nodeLo + t] = lo + sc[t] - own;
  if (b == NBKT - 1 && t == 0) rowStart[N] = E;
  if (t < 512) sc[t] -= own;  // exclusive bucket-local cursors
  __syncthreads();
  if (cnt <= STG_CAP) {
    for (int i = lo + t; i < hi; i += SORT_T) {
      int pk = epk[i];
      int pos = atomicAdd(&sc[pk >> 17], 1);
      stg[pos] = pk & 0x1FFFF;
    }
    __syncthreads();
    for (int i = t; i < cnt; i += SORT_T) colIdx[lo + i] = stg[i];  // coalesced
  } else {  // fallback (never taken at this E/NBKT)
    for (int i = lo + t; i < hi; i += SORT_T) {
      int pk = epk[i];
      int pos = lo + atomicAdd(&sc[pk >> 17], 1);
      colIdx[pos] = pk & 0x1FFFF;
    }
  }
}

// ================= node transform (layer 1): SPLIT threads/node =================

template <int IN, int H, int C, int SPLIT, bool NT>
__global__ void k_node(const float* __restrict__ xin, const float* __restrict__ W,
                       const float* __restrict__ a_src, const float* __restrict__ a_dst,
                       _Float16* __restrict__ hout, float* __restrict__ as_,
                       float* __restrict__ ad_, int N) {
  constexpr int OUT = H * C;
  constexpr int PIN4 = IN / SPLIT / 4;
  constexpr int NPB = TB / SPLIT;
  __shared__ float Ws[IN * OUT];
  __shared__ float As[OUT], Ad[OUT];
  for (int i = threadIdx.x; i < IN * OUT; i += blockDim.x) Ws[i] = W[i];
  if (threadIdx.x < OUT) {
    As[threadIdx.x] = a_src[threadIdx.x];
    Ad[threadIdx.x] = a_dst[threadIdx.x];
  }
  __syncthreads();
  const int j = threadIdx.x & (SPLIT - 1);
  const int n = blockIdx.x * NPB + threadIdx.x / SPLIT;
  if (n >= N) return;
  float acc[OUT];
#pragma unroll
  for (int q = 0; q < OUT; ++q) acc[q] = 0.f;
  const f4v* x4 = reinterpret_cast<const f4v*>(xin + (size_t)n * IN + j * (IN / SPLIT));
#pragma unroll
  for (int k4 = 0; k4 < PIN4; ++k4) {
    f4v xv = NT ? __builtin_nontemporal_load(&x4[k4]) : x4[k4];
    const int kb = j * (IN / SPLIT) + 4 * k4;
#pragma unroll
    for (int q = 0; q < OUT; ++q) {
      acc[q] += xv[0] * Ws[(kb + 0) * OUT + q];
      acc[q] += xv[1] * Ws[(kb + 1) * OUT + q];
      acc[q] += xv[2] * Ws[(kb + 2) * OUT + q];
      acc[q] += xv[3] * Ws[(kb + 3) * OUT + q];
    }
  }
#pragma unroll
  for (int o = 1; o < SPLIT; o <<= 1) {
#pragma unroll
    for (int q = 0; q < OUT; ++q) acc[q] += __shfl_xor(acc[q], o);
  }
  constexpr int WCH = OUT / 4;
  if (j < WCH) {
    h4v v;
    v[0] = (_Float16)acc[4 * j + 0];
    v[1] = (_Float16)acc[4 * j + 1];
    v[2] = (_Float16)acc[4 * j + 2];
    v[3] = (_Float16)acc[4 * j + 3];
    reinterpret_cast<h4v*>(hout + (size_t)n * OUT)[j] = v;
  }
  if (j < H) {
    float ss = 0.f, dd = 0.f;
#pragma unroll
    for (int c = 0; c < C; ++c) {
      ss += acc[j * C + c] * As[j * C + c];
      dd += acc[j * C + c] * Ad[j * C + c];
    }
    as_[n * H + j] = ss;
    ad_[n * H + j] = dd;
  }
}

// ================= edge layer 1 + fused node transform 2 =================
// L=2 lanes x 16B h1 gathers, S=4 edge-split, int4 colIdx chunks. Epilogue:
// o1 = relu(agg/s + b1); h2 = o1@W2, as2/ad2 — written directly (no o1 array).

__global__ void k_edge12(const int* __restrict__ rowStart, const int* __restrict__ colIdx,
                         const _Float16* __restrict__ h1, const float* __restrict__ as_,
                         const float* __restrict__ ad_, const float* __restrict__ b1,
                         const float* __restrict__ W2, const float* __restrict__ as2w,
                         const float* __restrict__ ad2w, _Float16* __restrict__ h2,
                         float* __restrict__ as2, float* __restrict__ ad2, int N, int R8) {
  constexpr int L = 2, S = 4, LS = 8, NPB = TB / LS;
  __shared__ float Ws2[128], A2s[8], A2d[8], B1s[16];
  if (threadIdx.x < 128) Ws2[threadIdx.x] = W2[threadIdx.x];
  if (threadIdx.x < 8) {
    A2s[threadIdx.x] = as2w[threadIdx.x];
    A2d[threadIdx.x] = ad2w[threadIdx.x];
  }
  if (threadIdx.x < 16) B1s[threadIdx.x] = b1[threadIdx.x];
  __syncthreads();
  const int g = blockIdx.x & (NGRP - 1);
  const int lb = blockIdx.x / NGRP;
  const int lane = threadIdx.x % LS;
  const int sub = lane >> 1;
  const int j = lane & 1;
  const int n = g * R8 + lb * NPB + threadIdx.x / LS;
  const int nEnd = min((g + 1) * R8, N);
  if (n >= nEnd) return;
  const float adv = ad_[n * 2 + j];
  const int start = rowStart[n];
  const int end = rowStart[n + 1];
  float s = 0.f, acc[8];
#pragma unroll
  for (int q = 0; q < 8; ++q) acc[q] = 0.f;
  if (sub == 0) {  // self-loop
    float p = __expf(leaky(as_[n * 2 + j] + adv));
    h8v a0 = reinterpret_cast<const h8v*>(h1 + (size_t)n * 16)[j];
    s = p;
#pragma unroll
    for (int q = 0; q < 8; ++q) acc[q] = p * (float)a0[q];
  }
  const int base = start & ~3;
  const int nch = (end - base + 3) >> 2;
  for (int t = sub; t < nch; t += S) {
    const int i0 = base + 4 * t;
    i4v cv = *reinterpret_cast<const i4v*>(colIdx + i0);
#pragma unroll
    for (int k = 0; k < 4; ++k) {
      const bool ok = (i0 + k >= start) && (i0 + k < end);
      const int src = ok ? cv[k] : n;
      h8v hv = reinterpret_cast<const h8v*>(h1 + (size_t)src * 16)[j];
      float e = as_[src * 2 + j];
      float p = ok ? __expf(leaky(e + adv)) : 0.f;
      s += p;
#pragma unroll
      for (int q = 0; q < 8; ++q) acc[q] += p * (float)hv[q];
    }
  }
#pragma unroll
  for (int off = L; off < LS; off <<= 1) {
    s += __shfl_xor(s, off);
#pragma unroll
    for (int q = 0; q < 8; ++q) acc[q] += __shfl_xor(acc[q], off);
  }
  if (sub == 0) {
    float inv = 1.f / (s + 1e-16f);
    float o1v[8];
#pragma unroll
    for (int q = 0; q < 8; ++q) o1v[q] = fmaxf(acc[q] * inv + B1s[j * 8 + q], 0.f);
    float h2p[8];
#pragma unroll
    for (int q = 0; q < 8; ++q) {
      float tacc = 0.f;
#pragma unroll
      for (int c = 0; c < 8; ++c) tacc += o1v[c] * Ws2[(j * 8 + c) * 8 + q];
      h2p[q] = tacc;
    }
    float h2f[8];
#pragma unroll
    for (int q = 0; q < 8; ++q) h2f[q] = h2p[q] + __shfl_xor(h2p[q], 1);
    h4v v;
#pragma unroll
    for (int q = 0; q < 4; ++q) v[q] = (_Float16)h2f[j * 4 + q];
    reinterpret_cast<h4v*>(h2 + (size_t)n * 8)[j] = v;
    float ss = 0.f, dd = 0.f;
#pragma unroll
    for (int c = 0; c < 4; ++c) {
      ss += h2f[j * 4 + c] * A2s[j * 4 + c];
      dd += h2f[j * 4 + c] * A2d[j * 4 + c];
    }
    as2[n * 2 + j] = ss;
    ad2[n * 2 + j] = dd;
  }
}

// ================= edge layer 2 + fused node transform 3 =================
// L=2 lanes x 8B h2 gathers, S=4. Epilogue: o2 = relu(agg/s + b2);
// h3 = o2@W3, as3/ad3 — written directly (no o2 array).

__global__ void k_edge23(const int* __restrict__ rowStart, const int* __restrict__ colIdx,
                         const _Float16* __restrict__ h2, const float* __restrict__ as_,
                         const float* __restrict__ ad_, const float* __restrict__ b2,
                         const float* __restrict__ W3, const float* __restrict__ as3w,
                         const float* __restrict__ ad3w, _Float16* __restrict__ h3,
                         float* __restrict__ as3, float* __restrict__ ad3, int N, int R8) {
  constexpr int L = 2, S = 4, LS = 8, NPB = TB / LS;
  __shared__ float Ws3[32], A3s[4], A3d[4], B2s[8];
  if (threadIdx.x < 32) Ws3[threadIdx.x] = W3[threadIdx.x];
  if (threadIdx.x < 4) {
    A3s[threadIdx.x] = as3w[threadIdx.x];
    A3d[threadIdx.x] = ad3w[threadIdx.x];
  }
  if (threadIdx.x < 8) B2s[threadIdx.x] = b2[threadIdx.x];
  __syncthreads();
  const int g = blockIdx.x & (NGRP - 1);
  const int lb = blockIdx.x / NGRP;
  const int lane = threadIdx.x % LS;
  const int sub = lane >> 1;
  const int j = lane & 1;
  const int n = g * R8 + lb * NPB + threadIdx.x / LS;
  const int nEnd = min((g + 1) * R8, N);
  if (n >= nEnd) return;
  const float adv = ad_[n * 2 + j];
  const int start = rowStart[n];
  const int end = rowStart[n + 1];
  float s = 0.f, acc[4];
#pragma unroll
  for (int q = 0; q < 4; ++q) acc[q] = 0.f;
  if (sub == 0) {
    float p = __expf(leaky(as_[n * 2 + j] + adv));
    h4v a0 = reinterpret_cast<const h4v*>(h2 + (size_t)n * 8)[j];
    s = p;
#pragma unroll
    for (int q = 0; q < 4; ++q) acc[q] = p * (float)a0[q];
  }
  const int base = start & ~3;
  const int nch = (end - base + 3) >> 2;
  for (int t = sub; t < nch; t += S) {
    const int i0 = base + 4 * t;
    i4v cv = *reinterpret_cast<const i4v*>(colIdx + i0);
#pragma unroll
    for (int k = 0; k < 4; ++k) {
      const bool ok = (i0 + k >= start) && (i0 + k < end);
      const int src = ok ? cv[k] : n;
      h4v hv = reinterpret_cast<const h4v*>(h2 + (size_t)src * 8)[j];
      float e = as_[src * 2 + j];
      float p = ok ? __expf(leaky(e + adv)) : 0.f;
      s += p;
#pragma unroll
      for (int q = 0; q < 4; ++q) acc[q] += p * (float)hv[q];
    }
  }
#pragma unroll
  for (int off = L; off < LS; off <<= 1) {
    s += __shfl_xor(s, off);
#pragma unroll
    for (int q = 0; q < 4; ++q) acc[q] += __shfl_xor(acc[q], off);
  }
  if (sub == 0) {
    float inv = 1.f / (s + 1e-16f);
    float o2v[4];
#pragma unroll
    for (int q = 0; q < 4; ++q) o2v[q] = fmaxf(acc[q] * inv + B2s[j * 4 + q], 0.f);
    float h3p[4];
#pragma unroll
    for (int q = 0; q < 4; ++q) {
      float tacc = 0.f;
#pragma unroll
      for (int c = 0; c < 4; ++c) tacc += o2v[c] * Ws3[(j * 4 + c) * 4 + q];
      h3p[q] = tacc;
    }
    float h3f[4];
#pragma unroll
    for (int q = 0; q < 4; ++q) h3f[q] = h3p[q] + __shfl_xor(h3p[q], 1);
    if (j == 0) {
      h4v v;
#pragma unroll
      for (int q = 0; q < 4; ++q) v[q] = (_Float16)h3f[q];
      reinterpret_cast<h4v*>(h3)[n] = v;
      float ss = 0.f, dd = 0.f;
#pragma unroll
      for (int c = 0; c < 4; ++c) {
        ss += h3f[c] * A3s[c];
        dd += h3f[c] * A3d[c];
      }
      as3[n] = ss;
      ad3[n] = dd;
    }
  }
}

// ================= edge layer 3 + fused classifier; S=8, chunked =================

__global__ void k_edge3(const int* __restrict__ rowStart, const int* __restrict__ colIdx,
                        const _Float16* __restrict__ hfeat, const float* __restrict__ as_,
                        const float* __restrict__ ad_, const float* __restrict__ b3,
                        const float* __restrict__ Wc, const float* __restrict__ bc,
                        float* __restrict__ out, int N, int R8) {
  constexpr int S = 8;
  constexpr int NPB = TB / S;
  const int g = blockIdx.x & (NGRP - 1);
  const int lb = blockIdx.x / NGRP;
  const int sub = threadIdx.x % S;
  const int n = g * R8 + lb * NPB + threadIdx.x / S;
  const int nEnd = min((g + 1) * R8, N);
  if (n >= nEnd) return;
  const float adv = ad_[n];
  const int start = rowStart[n];
  const int end = rowStart[n + 1];
  float s = 0.f, acc0 = 0.f, acc1 = 0.f, acc2 = 0.f, acc3 = 0.f;
  if (sub == 0) {
    float p = __expf(leaky(as_[n] + adv));
    h4v a0 = reinterpret_cast<const h4v*>(hfeat)[n];
    s = p;
    acc0 = p * (float)a0[0];
    acc1 = p * (float)a0[1];
    acc2 = p * (float)a0[2];
    acc3 = p * (float)a0[3];
  }
  const int base = start & ~3;
  const int nch = (end - base + 3) >> 2;
  for (int t = sub; t < nch; t += S) {
    const int i0 = base + 4 * t;
    i4v cv = *reinterpret_cast<const i4v*>(colIdx + i0);
#pragma unroll
    for (int k = 0; k < 4; ++k) {
      const bool ok = (i0 + k >= start) && (i0 + k < end);
      const int src = ok ? cv[k] : n;
      h4v hv = reinterpret_cast<const h4v*>(hfeat)[src];
      float e = as_[src];
      float p = ok ? __expf(leaky(e + adv)) : 0.f;
      s += p;
      acc0 += p * (float)hv[0];
      acc1 += p * (float)hv[1];
      acc2 += p * (float)hv[2];
      acc3 += p * (float)hv[3];
    }
  }
#pragma unroll
  for (int off = 1; off < S; off <<= 1) {
    s += __shfl_xor(s, off);
    acc0 += __shfl_xor(acc0, off);
    acc1 += __shfl_xor(acc1, off);
    acc2 += __shfl_xor(acc2, off);
    acc3 += __shfl_xor(acc3, off);
  }
  if (sub == 0) {
    float inv = 1.f / (s + 1e-16f);
    float o0 = acc0 * inv + b3[0];
    float o1 = acc1 * inv + b3[1];
    float o2 = acc2 * inv + b3[2];
    float o3 = acc3 * inv + b3[3];
    float2 r;
    r.x = o0 * Wc[0] + o1 * Wc[2] + o2 * Wc[4] + o3 * Wc[6] + bc[0];
    r.y = o0 * Wc[1] + o1 * Wc[3] + o2 * Wc[5] + o3 * Wc[7] + bc[1];
    reinterpret_cast<float2*>(out)[n] = r;
  }
}

// ================= launch =================

extern "C" void kernel_launch(void* const* d_in, const int* in_sizes, int n_in,
                              void* d_out, int out_size, void* d_ws, size_t ws_size,
                              hipStream_t stream) {
  const float* x    = (const float*)d_in[0];
  const int*   ei   = (const int*)d_in[1];
  const float* W1   = (const float*)d_in[2];
  const float* as1w = (const float*)d_in[3];
  const float* ad1w = (const float*)d_in[4];
  const float* b1   = (const float*)d_in[5];
  const float* W2   = (const float*)d_in[6];
  const float* as2w = (const float*)d_in[7];
  const float* ad2w = (const float*)d_in[8];
  const float* b2   = (const float*)d_in[9];
  const float* W3   = (const float*)d_in[10];
  const float* as3w = (const float*)d_in[11];
  const float* ad3w = (const float*)d_in[12];
  const float* b3   = (const float*)d_in[13];
  const float* Wc   = (const float*)d_in[14];
  const float* bc   = (const float*)d_in[15];
  float* out = (float*)d_out;

  const int N = in_sizes[0] / 128;
  const int E = in_sizes[1] / 2;
  const int* srcA = ei;
  const int* dstA = ei + E;

  char* p = (char*)d_ws;
  auto alloc = [&](size_t bytes) -> void* {
    void* r = (void*)p;
    p += (bytes + 255) & ~(size_t)255;
    return r;
  };
  int* cnt        = (int*)alloc((size_t)NBKT * NB_P * 4);
  int* off        = (int*)alloc((size_t)NBKT * NB_P * 4);
  int* colTotal   = (int*)alloc(NBKT * 4);
  int* bucketBase = (int*)alloc((NBKT + 1) * 4);
  int* rowStart   = (int*)alloc((size_t)(N + 1) * 4);
  int* epk        = (int*)alloc((size_t)E * 4);
  int* colIdx     = (int*)alloc((size_t)E * 4 + 256);
  _Float16* h1 = (_Float16*)alloc((size_t)N * 16 * 2);
  float* as1 = (float*)alloc((size_t)N * 2 * 4);
  float* ad1 = (float*)alloc((size_t)N * 2 * 4);
  _Float16* h2 = (_Float16*)alloc((size_t)N * 8 * 2);
  float* as2 = (float*)alloc((size_t)N * 2 * 4);
  float* ad2 = (float*)alloc((size_t)N * 2 * 4);
  _Float16* h3 = (_Float16*)alloc((size_t)N * 4 * 2);
  float* as3 = (float*)alloc((size_t)N * 4);
  float* ad3 = (float*)alloc((size_t)N * 4);

  const int R   = (N + NBKT - 1) / NBKT;                       // nodes per bucket (391)
  const unsigned M = (unsigned)(((1ULL << 32) + R - 1) / R);   // exact /R via __umulhi
  const int R8  = R * (NBKT / NGRP);                           // nodes per XCD (12512)
  const int E4  = E >> 2;
  const int CH4 = (E4 + NB_P - 1) / NB_P;

  // CSR build (no global atomics; coalesced colIdx write)
  k_bcount<<<NB_P, TBP, 0, stream>>>(dstA, cnt, E4, E, M, CH4);
  k_bscan1<<<NBKT, NB_P, 0, stream>>>(cnt, off, colTotal);
  k_bscan2<<<1, NBKT, 0, stream>>>(colTotal, bucketBase);
  k_bscatter<<<NB_P, TBP, 0, stream>>>(srcA, dstA, off, bucketBase, epk, E4, E, M, R, CH4);
  k_bsort<<<NBKT, SORT_T, 0, stream>>>(epk, bucketBase, rowStart, colIdx, N, R, E);

  const int nb1 = (N + (TB / 4) - 1) / (TB / 4);
  const int ge = NGRP * ((R8 + (TB / 8) - 1) / (TB / 8));  // LS=8 -> 32 nodes/block

  k_node<128, 2, 8, 4, true><<<nb1, TB, 0, stream>>>(x, W1, as1w, ad1w, h1, as1, ad1, N);
  k_edge12<<<ge, TB, 0, stream>>>(rowStart, colIdx, h1, as1, ad1, b1, W2, as2w, ad2w,
                                  h2, as2, ad2, N, R8);
  k_edge23<<<ge, TB, 0, stream>>>(rowStart, colIdx, h2, as2, ad2, b2, W3, as3w, ad3w,
                                  h3, as3, ad3, N, R8);
  k_edge3<<<ge, TB, 0, stream>>>(rowStart, colIdx, h3, as3, ad3, b3, Wc, bc, out, N, R8);
}